// Round 1
// baseline (433.925 us; speedup 1.0000x reference)
//
#include <hip/hip_runtime.h>

#define NUM_NODES 100000
#define NODE_DIM 32

// ---------------------------------------------------------------------------
// Kernel 1: zero the output accumulator (d_out) and the count buffer (d_ws).
// ---------------------------------------------------------------------------
__global__ void mp_zero_kernel(float4* __restrict__ out4,
                               float4* __restrict__ cnt4,
                               int n_out4, int n_cnt4) {
    int t = blockIdx.x * blockDim.x + threadIdx.x;
    if (t < n_out4) {
        out4[t] = make_float4(0.f, 0.f, 0.f, 0.f);
    }
    int u = t - n_out4;
    if (u >= 0 && u < n_cnt4) {
        cnt4[u] = make_float4(0.f, 0.f, 0.f, 0.f);
    }
}

// ---------------------------------------------------------------------------
// Kernel 2: per-edge message computation + scatter-add.
// 8 lanes per edge; lane j owns output features [4j, 4j+3].
// msg[f] = sum_d x[src][d] * A[e][d][f];  atomicAdd into out[dst].
// ---------------------------------------------------------------------------
__global__ void mp_edge_kernel(const float* __restrict__ node_states,
                               const int* __restrict__ edge_index,
                               const float4* __restrict__ a4,
                               float* __restrict__ out_sum,
                               float* __restrict__ counts,
                               int n_edges) {
    int t = blockIdx.x * blockDim.x + threadIdx.x;
    int e = t >> 3;
    if (e >= n_edges) return;
    int j = t & 7;

    int src = edge_index[2 * e];
    int dst = edge_index[2 * e + 1];

    // 8 lanes cooperatively load x[src] (32 floats, 128B coalesced).
    float4 x4 = reinterpret_cast<const float4*>(node_states)[src * 8 + j];
    float xs[4] = {x4.x, x4.y, x4.z, x4.w};

    const float4* A = a4 + (size_t)e * 256;  // A[e] = 32x32 floats = 256 float4
    float4 acc = make_float4(0.f, 0.f, 0.f, 0.f);

#pragma unroll
    for (int d = 0; d < 32; ++d) {
        // broadcast x[src][d] across the 8-lane group (static index after unroll)
        float xd = __shfl(xs[d & 3], d >> 2, 8);
        float4 a = A[d * 8 + j];  // A[e][d][4j .. 4j+3], 128B/row coalesced
        acc.x = fmaf(xd, a.x, acc.x);
        acc.y = fmaf(xd, a.y, acc.y);
        acc.z = fmaf(xd, a.z, acc.z);
        acc.w = fmaf(xd, a.w, acc.w);
    }

    float* o = out_sum + (size_t)dst * NODE_DIM + j * 4;
    atomicAdd(o + 0, acc.x);
    atomicAdd(o + 1, acc.y);
    atomicAdd(o + 2, acc.z);
    atomicAdd(o + 3, acc.w);
    if (j == 0) atomicAdd(counts + dst, 1.0f);
}

// ---------------------------------------------------------------------------
// Kernel 3: out = relu(out / max(count,1) + bias)
// ---------------------------------------------------------------------------
__global__ void mp_finalize_kernel(float4* __restrict__ out4,
                                   const float* __restrict__ counts,
                                   const float4* __restrict__ bias4,
                                   int n_nodes) {
    int t = blockIdx.x * blockDim.x + threadIdx.x;
    if (t >= n_nodes * 8) return;
    int n = t >> 3;
    int j = t & 7;
    float c = fmaxf(counts[n], 1.0f);
    float inv = 1.0f / c;
    float4 s = out4[t];
    float4 b = bias4[j];
    float4 r;
    r.x = fmaxf(fmaf(s.x, inv, b.x), 0.f);
    r.y = fmaxf(fmaf(s.y, inv, b.y), 0.f);
    r.z = fmaxf(fmaf(s.z, inv, b.z), 0.f);
    r.w = fmaxf(fmaf(s.w, inv, b.w), 0.f);
    out4[t] = r;
}

extern "C" void kernel_launch(void* const* d_in, const int* in_sizes, int n_in,
                              void* d_out, int out_size, void* d_ws, size_t ws_size,
                              hipStream_t stream) {
    const float* node_states = (const float*)d_in[0];
    const int*   edge_index  = (const int*)d_in[1];
    const float* a_in        = (const float*)d_in[2];
    const float* bias        = (const float*)d_in[3];

    int n_edges = in_sizes[1] / 2;          // 500000
    int n_nodes = in_sizes[0] / NODE_DIM;   // 100000

    float* out_sum = (float*)d_out;          // accumulate sums in-place
    float* counts  = (float*)d_ws;           // n_nodes floats of scratch

    // 1) zero accumulators
    int n_out4 = n_nodes * (NODE_DIM / 4);   // 800000
    int n_cnt4 = (n_nodes + 3) / 4;          // 25000
    {
        int total = n_out4 + n_cnt4;
        int blocks = (total + 255) / 256;
        mp_zero_kernel<<<blocks, 256, 0, stream>>>(
            (float4*)out_sum, (float4*)counts, n_out4, n_cnt4);
    }

    // 2) edge messages + scatter
    {
        long long total = (long long)n_edges * 8;
        int blocks = (int)((total + 255) / 256);
        mp_edge_kernel<<<blocks, 256, 0, stream>>>(
            node_states, edge_index, (const float4*)a_in,
            out_sum, counts, n_edges);
    }

    // 3) mean + bias + relu
    {
        int total = n_nodes * 8;
        int blocks = (total + 255) / 256;
        mp_finalize_kernel<<<blocks, 256, 0, stream>>>(
            (float4*)out_sum, counts, (const float4*)bias, n_nodes);
    }
}

// Round 3
// 397.708 us; speedup vs baseline: 1.0911x; 1.0911x over previous
//
#include <hip/hip_runtime.h>

#define NUM_NODES 100000
#define NODE_DIM 32

typedef float floatx4 __attribute__((ext_vector_type(4)));

// ---------------------------------------------------------------------------
// Kernel 1: zero the output accumulator (d_out) and the count buffer (d_ws).
// ---------------------------------------------------------------------------
__global__ void mp_zero_kernel(float4* __restrict__ out4,
                               float4* __restrict__ cnt4,
                               int n_out4, int n_cnt4) {
    int t = blockIdx.x * blockDim.x + threadIdx.x;
    if (t < n_out4) {
        out4[t] = make_float4(0.f, 0.f, 0.f, 0.f);
    }
    int u = t - n_out4;
    if (u >= 0 && u < n_cnt4) {
        cnt4[u] = make_float4(0.f, 0.f, 0.f, 0.f);
    }
}

// ---------------------------------------------------------------------------
// Kernel 2: per-edge message computation + scatter-add.
// Grid-stride: 8 lanes per edge-slot; lane j owns output features [4j,4j+3].
// Next edge's (edge_index, x) chain is prefetched while current edge's
// A-loads/FMAs execute. a_in is loaded nontemporally (streamed once).
// ---------------------------------------------------------------------------
__global__ void mp_edge_kernel(const float* __restrict__ node_states,
                               const int* __restrict__ edge_index,
                               const floatx4* __restrict__ a4,
                               float* __restrict__ out_sum,
                               float* __restrict__ counts,
                               int n_edges) {
    int tid = blockIdx.x * blockDim.x + threadIdx.x;
    int j = tid & 7;
    int group = tid >> 3;
    int ngroups = (gridDim.x * blockDim.x) >> 3;

    int e = group;
    if (e >= n_edges) return;

    // prologue: load first edge's index pair + x row
    int2 ei = *reinterpret_cast<const int2*>(edge_index + 2 * (size_t)e);
    float4 x4 = reinterpret_cast<const float4*>(node_states)[(size_t)ei.x * 8 + j];

    while (e < n_edges) {
        int en = e + ngroups;
        int2 ei_n;
        float4 x4_n;
        if (en < n_edges) {
            // prefetch next edge's chained loads; overlaps with A-loads + FMAs
            ei_n = *reinterpret_cast<const int2*>(edge_index + 2 * (size_t)en);
            x4_n = reinterpret_cast<const float4*>(node_states)[(size_t)ei_n.x * 8 + j];
        }

        float xs[4] = {x4.x, x4.y, x4.z, x4.w};
        const floatx4* A = a4 + (size_t)e * 256;  // 32x32 floats = 256 float4
        float4 acc = make_float4(0.f, 0.f, 0.f, 0.f);

#pragma unroll
        for (int d = 0; d < 32; ++d) {
            float xd = __shfl(xs[d & 3], d >> 2, 8);
            floatx4 a = __builtin_nontemporal_load(&A[d * 8 + j]);
            acc.x = fmaf(xd, a.x, acc.x);
            acc.y = fmaf(xd, a.y, acc.y);
            acc.z = fmaf(xd, a.z, acc.z);
            acc.w = fmaf(xd, a.w, acc.w);
        }

        int dst = ei.y;
        float* o = out_sum + (size_t)dst * NODE_DIM + j * 4;
        atomicAdd(o + 0, acc.x);
        atomicAdd(o + 1, acc.y);
        atomicAdd(o + 2, acc.z);
        atomicAdd(o + 3, acc.w);
        if (j == 0) atomicAdd(counts + dst, 1.0f);

        e = en;
        ei = ei_n;
        x4 = x4_n;
    }
}

// ---------------------------------------------------------------------------
// Kernel 3: out = relu(out / max(count,1) + bias)
// ---------------------------------------------------------------------------
__global__ void mp_finalize_kernel(float4* __restrict__ out4,
                                   const float* __restrict__ counts,
                                   const float4* __restrict__ bias4,
                                   int n_nodes) {
    int t = blockIdx.x * blockDim.x + threadIdx.x;
    if (t >= n_nodes * 8) return;
    int n = t >> 3;
    int j = t & 7;
    float c = fmaxf(counts[n], 1.0f);
    float inv = 1.0f / c;
    float4 s = out4[t];
    float4 b = bias4[j];
    float4 r;
    r.x = fmaxf(fmaf(s.x, inv, b.x), 0.f);
    r.y = fmaxf(fmaf(s.y, inv, b.y), 0.f);
    r.z = fmaxf(fmaf(s.z, inv, b.z), 0.f);
    r.w = fmaxf(fmaf(s.w, inv, b.w), 0.f);
    out4[t] = r;
}

extern "C" void kernel_launch(void* const* d_in, const int* in_sizes, int n_in,
                              void* d_out, int out_size, void* d_ws, size_t ws_size,
                              hipStream_t stream) {
    const float* node_states = (const float*)d_in[0];
    const int*   edge_index  = (const int*)d_in[1];
    const float* a_in        = (const float*)d_in[2];
    const float* bias        = (const float*)d_in[3];

    int n_edges = in_sizes[1] / 2;          // 500000
    int n_nodes = in_sizes[0] / NODE_DIM;   // 100000

    float* out_sum = (float*)d_out;          // accumulate sums in-place
    float* counts  = (float*)d_ws;           // n_nodes floats of scratch

    // 1) zero accumulators
    int n_out4 = n_nodes * (NODE_DIM / 4);   // 800000
    int n_cnt4 = (n_nodes + 3) / 4;          // 25000
    {
        int total = n_out4 + n_cnt4;
        int blocks = (total + 255) / 256;
        mp_zero_kernel<<<blocks, 256, 0, stream>>>(
            (float4*)out_sum, (float4*)counts, n_out4, n_cnt4);
    }

    // 2) edge messages + scatter (grid-stride; ~8 edges per 8-lane group)
    {
        int blocks = 2048;  // 2048*256/8 = 65536 groups -> ~7.6 edges/group
        mp_edge_kernel<<<blocks, 256, 0, stream>>>(
            node_states, edge_index, (const floatx4*)a_in,
            out_sum, counts, n_edges);
    }

    // 3) mean + bias + relu
    {
        int total = n_nodes * 8;
        int blocks = (total + 255) / 256;
        mp_finalize_kernel<<<blocks, 256, 0, stream>>>(
            (float4*)out_sum, counts, (const float4*)bias, n_nodes);
    }
}